// Round 11
// baseline (93.032 us; speedup 1.0000x reference)
//
#include <hip/hip_runtime.h>

#define BB    8
#define CC    256
#define HWN   16384       // 128*128
#define PP    30
#define PPAD  32          // padded proto count (2 zero rows)
#define KD    128
#define GG    5
// d_out float offsets
#define OFF_Q   (33554432u)             // 8*256*128*128
#define OFF_SIM (OFF_Q + 30720u)        // + 30*8*128

typedef float  f32x4 __attribute__((ext_vector_type(4)));
typedef float  f32x4a __attribute__((ext_vector_type(4)));
typedef short  short8 __attribute__((ext_vector_type(8)));

static __device__ __forceinline__ short f2bf(float f) {   // f32 -> bf16 RNE
    unsigned u = __float_as_uint(f);
    u += 0x7fffu + ((u >> 16) & 1u);
    return (short)(u >> 16);
}

// ---- kernel 1: q-projection + A in bf16 16x16x32-fragment order + c0 -------
// A[b,p,c] = sum_k q[p,b,k]*Wk[k,c]  (rows 30,31 zero)
// A-frag layout for v_mfma_f32_16x16x32_bf16 (half h = p>>4):
//   kb = c>>5, lane = (p&15) + 16*((c>>3)&3), j = c&7
//   Afrag[(((b*2 + h)*8 + kb)*64 + lane)*8 + j]
__global__ __launch_bounds__(256) void proj_kernel(
    const float* __restrict__ proto,  // [P,B,C]
    const float* __restrict__ Wq,     // [6,128,C]
    const float* __restrict__ bq,     // [6,128]
    const float* __restrict__ Wk,     // [128,C]
    const float* __restrict__ bk,     // [128]
    float* __restrict__ qout,         // [P,B,128] (into d_out)
    short* __restrict__ Afrag,        // [B,2,8,64,8] bf16 (ws)
    float* __restrict__ c0)           // [B,PPAD]   (ws)
{
    const int pb = blockIdx.x;        // p*B + b  (p in [0,32))
    const int p = pb / BB, b = pb % BB;
    const int tid = threadIdx.x;      // = channel c

    const int kb = tid >> 5, sub = (tid >> 3) & 3, j = tid & 7;
    const int lane = (p & 15) + 16 * sub;
    const size_t fidx = (((size_t)(b * 2 + (p >> 4)) * 8 + kb) * 64 + lane) * 8 + j;

    if (p >= PP) {                    // pad rows
        Afrag[fidx] = 0;
        if (tid == 0) c0[b * PPAD + p] = -1e30f;
        return;
    }
    const int g = p / GG;

    __shared__ float ps[CC];
    __shared__ float qs[KD];

    for (int c = tid; c < CC; c += 256)
        ps[c] = proto[(size_t)(p * BB + b) * CC + c];
    __syncthreads();

    if (tid < KD) {
        const float* wrow = Wq + (size_t)(g * KD + tid) * CC;
        float a = 0.f;
        #pragma unroll 4
        for (int c = 0; c < CC; ++c) a += ps[c] * wrow[c];
        a += bq[g * KD + tid];
        qout[(size_t)(p * BB + b) * KD + tid] = a;
        qs[tid] = a;
    }
    __syncthreads();

    float a = 0.f;
    #pragma unroll 4
    for (int k = 0; k < KD; ++k) a += qs[k] * Wk[k * CC + tid];
    Afrag[fidx] = f2bf(a);

    if (tid == 0) {
        float s = 0.f;
        for (int k = 0; k < KD; ++k) s += qs[k] * bk[k];
        c0[b * PPAD + p] = s;
    }
}

// ---- kernel 2: MFMA sim + in-register softmax + weighted output ------------
// Block = 4 waves x 16 positions = 64 positions; grid 2048 -> 8 blocks/CU,
// 32 waves/CU budget. Per wave: 8 K-steps x 2 mfma_f32_16x16x32_bf16
// (proto halves share the X B-fragment). Softmax reduced with shfl_xor.
__global__ __launch_bounds__(256) void fused_kernel(
    const float* __restrict__ X,     // [B,C,HW]
    const short* __restrict__ Afrag, // [B,2,8,64,8] bf16
    const float* __restrict__ c0,    // [B,PPAD]
    float* __restrict__ out0,        // [B,C,HW]
    float* __restrict__ sim)         // [B,PP,HW]
{
    const int b    = blockIdx.y;
    const int tid  = threadIdx.x;
    const int lane = tid & 63;
    const int wid  = tid >> 6;
    const int col  = lane & 15;       // position within wave tile
    const int kgrp = lane >> 4;       // 0..3 (k-subchunk)
    const int n0   = blockIdx.x * 64;
    const int nw   = n0 + wid * 16;   // wave's 16 positions

    __shared__ float c0s[PPAD];
    __shared__ float wbuf[64];

    if (tid < PPAD) c0s[tid] = c0[b * PPAD + tid];

    const short8* af8 = (const short8*)Afrag;
    const size_t afbase = (size_t)b * 2 * 8 * 64;

    f32x4a accA = {}, accB = {};
    const float* xcol = X + (size_t)b * CC * HWN + nw + col;

    #pragma unroll 2
    for (int kb = 0; kb < 8; ++kb) {
        const short8 afA = af8[afbase + (size_t)kb * 64 + lane];
        const short8 afB = af8[afbase + (size_t)(8 + kb) * 64 + lane];
        float xf[8];
        #pragma unroll
        for (int j = 0; j < 8; ++j)   // B-frag: k = kgrp*8+j, n = col
            xf[j] = xcol[(size_t)(kb * 32 + kgrp * 8 + j) * HWN];
        short8 bfr;
        #pragma unroll
        for (int j = 0; j < 8; ++j) bfr[j] = f2bf(xf[j]);
        accA = __builtin_amdgcn_mfma_f32_16x16x32_bf16(afA, bfr, accA, 0, 0, 0);
        accB = __builtin_amdgcn_mfma_f32_16x16x32_bf16(afB, bfr, accB, 0, 0, 0);
    }
    __syncthreads();                  // c0s ready

    // C/D: col = lane&15, row = (lane>>4)*4 + r; accA rows=protos, accB +16
    float v[8];
    float pm = -1e30f;
    #pragma unroll
    for (int r = 0; r < 4; ++r) {
        const int row = kgrp * 4 + r;
        const float tA = accA[r] + c0s[row];
        const float tB = accB[r] + c0s[row + 16];
        v[r] = tA;
        v[r + 4] = tB;
        pm = fmaxf(pm, fmaxf(tA, tB));
        sim[((size_t)b * PP + row) * HWN + nw + col] = tA;
        if (row + 16 < PP)
            sim[((size_t)b * PP + row + 16) * HWN + nw + col] = tB;
    }
    // cross-lane max over the 4 k-groups (pos fixed = col)
    float m = pm;
    m = fmaxf(m, __shfl_xor(m, 16));
    m = fmaxf(m, __shfl_xor(m, 32));

    float s = 0.f;
    #pragma unroll
    for (int r = 0; r < 8; ++r)       // pads: exp(-huge) = 0
        s += __expf((v[r] - m) * (1.f / 6.f));
    s += __shfl_xor(s, 16);
    s += __shfl_xor(s, 32);
    const float w = 1.f / s;          // max_p softmax == 1/sum exp

    if (lane < 16) wbuf[wid * 16 + lane] = w;
    __syncthreads();

    // weighted output: thread t -> pos-quad (t&15), channels (t>>4)*16+i
    const int pq = tid & 15;
    const int cg = tid >> 4;
    const f32x4 w4 = *(const f32x4*)(&wbuf[pq * 4]);
    const float* xb = X    + (size_t)b * CC * HWN + n0 + pq * 4;
    float*       ob = out0 + (size_t)b * CC * HWN + n0 + pq * 4;
    #pragma unroll 4
    for (int i = 0; i < 16; ++i) {
        const size_t off = (size_t)(cg * 16 + i) * HWN;
        f32x4 x = __builtin_nontemporal_load((const f32x4*)(xb + off));
        f32x4 o = x * w4;
        __builtin_nontemporal_store(o, (f32x4*)(ob + off));
    }
}

extern "C" void kernel_launch(void* const* d_in, const int* in_sizes, int n_in,
                              void* d_out, int out_size, void* d_ws, size_t ws_size,
                              hipStream_t stream) {
    const float* X     = (const float*)d_in[0];
    const float* proto = (const float*)d_in[1];
    const float* Wk    = (const float*)d_in[2];
    const float* bk    = (const float*)d_in[3];
    const float* Wq    = (const float*)d_in[4];
    const float* bq    = (const float*)d_in[5];

    float* out  = (float*)d_out;
    float* qout = out + OFF_Q;
    float* sim  = out + OFF_SIM;

    short* Afrag = (short*)d_ws;                        // 8*2*8*64*8 = 65536
    float* c0    = (float*)(Afrag + BB * 2 * 8 * 64 * 8);  // 256 floats

    proj_kernel<<<PPAD * BB, 256, 0, stream>>>(proto, Wq, bq, Wk, bk, qout, Afrag, c0);

    dim3 grid(HWN / 64, BB);                            // 256 x 8 = 2048 blocks
    fused_kernel<<<grid, 256, 0, stream>>>(X, Afrag, c0, out, sim);
}

// Round 12
// 91.508 us; speedup vs baseline: 1.0167x; 1.0167x over previous
//
#include <hip/hip_runtime.h>

#define BB    8
#define CC    256
#define HWN   16384       // 128*128
#define PP    30
#define PPAD  32          // padded proto count (2 zero rows)
#define KD    128
#define GG    5
// d_out float offsets
#define OFF_Q   (33554432u)             // 8*256*128*128
#define OFF_SIM (OFF_Q + 30720u)        // + 30*8*128

typedef float  f32x4 __attribute__((ext_vector_type(4)));
typedef short  short8 __attribute__((ext_vector_type(8)));

static __device__ __forceinline__ short f2bf(float f) {   // f32 -> bf16 RNE
    unsigned u = __float_as_uint(f);
    u += 0x7fffu + ((u >> 16) & 1u);
    return (short)(u >> 16);
}

// ---- kernel 1: q-projection + A in bf16 16x16x32-fragment order + c0 -------
// A[b,p,c] = sum_k q[p,b,k]*Wk[k,c]  (rows 30,31 zero)
// A-frag layout for v_mfma_f32_16x16x32_bf16 (half h = p>>4):
//   kb = c>>5, lane = (p&15) + 16*((c>>3)&3), j = c&7
//   Afrag[(((b*2 + h)*8 + kb)*64 + lane)*8 + j]
__global__ __launch_bounds__(256) void proj_kernel(
    const float* __restrict__ proto,  // [P,B,C]
    const float* __restrict__ Wq,     // [6,128,C]
    const float* __restrict__ bq,     // [6,128]
    const float* __restrict__ Wk,     // [128,C]
    const float* __restrict__ bk,     // [128]
    float* __restrict__ qout,         // [P,B,128] (into d_out)
    short* __restrict__ Afrag,        // [B,2,8,64,8] bf16 (ws)
    float* __restrict__ c0)           // [B,PPAD]   (ws)
{
    const int pb = blockIdx.x;        // p*B + b  (p in [0,32))
    const int p = pb / BB, b = pb % BB;
    const int tid = threadIdx.x;      // = channel c

    const int kb = tid >> 5, sub = (tid >> 3) & 3, j = tid & 7;
    const int lane = (p & 15) + 16 * sub;
    const size_t fidx = (((size_t)(b * 2 + (p >> 4)) * 8 + kb) * 64 + lane) * 8 + j;

    if (p >= PP) {                    // pad rows
        Afrag[fidx] = 0;
        if (tid == 0) c0[b * PPAD + p] = -1e30f;
        return;
    }
    const int g = p / GG;

    __shared__ float ps[CC];
    __shared__ float qs[KD];

    for (int c = tid; c < CC; c += 256)
        ps[c] = proto[(size_t)(p * BB + b) * CC + c];
    __syncthreads();

    if (tid < KD) {
        const float* wrow = Wq + (size_t)(g * KD + tid) * CC;
        float a = 0.f;
        #pragma unroll 4
        for (int c = 0; c < CC; ++c) a += ps[c] * wrow[c];
        a += bq[g * KD + tid];
        qout[(size_t)(p * BB + b) * KD + tid] = a;
        qs[tid] = a;
    }
    __syncthreads();

    float a = 0.f;
    #pragma unroll 4
    for (int k = 0; k < KD; ++k) a += qs[k] * Wk[k * CC + tid];
    Afrag[fidx] = f2bf(a);

    if (tid == 0) {
        float s = 0.f;
        for (int k = 0; k < KD; ++k) s += qs[k] * bk[k];
        c0[b * PPAD + p] = s;
    }
}

// ---- kernel 2 (A): MFMA sim + in-register softmax -> w[B,HW] ---------------
// Block = 4 waves x 16 positions; grid 2048. Per wave: 8 K-steps x 2
// mfma_f32_16x16x32_bf16 (proto halves share the X B-fragment). No out-pass:
// waves retire right after softmax. w written to ws for the streaming kernel.
__global__ __launch_bounds__(256) void sim_kernel(
    const float* __restrict__ X,     // [B,C,HW]
    const short* __restrict__ Afrag, // [B,2,8,64,8] bf16
    const float* __restrict__ c0,    // [B,PPAD]
    float* __restrict__ wq,          // [B,HWN] (ws)
    float* __restrict__ sim)         // [B,PP,HW]
{
    const int tid  = threadIdx.x;
    const int lane = tid & 63;
    const int wid  = tid >> 6;
    const int col  = lane & 15;       // position within wave tile
    const int kgrp = lane >> 4;       // 0..3 (k-subchunk)
    const int b    = blockIdx.y;
    const int nw   = blockIdx.x * 64 + wid * 16;   // wave's 16 positions

    __shared__ float c0s[PPAD];
    if (tid < PPAD) c0s[tid] = c0[b * PPAD + tid];

    const short8* af8 = (const short8*)Afrag;
    const size_t afbase = (size_t)b * 2 * 8 * 64;

    f32x4 accA = {}, accB = {};
    const float* xcol = X + (size_t)b * CC * HWN + nw + col;

    #pragma unroll 2
    for (int kb = 0; kb < 8; ++kb) {
        const short8 afA = af8[afbase + (size_t)kb * 64 + lane];
        const short8 afB = af8[afbase + (size_t)(8 + kb) * 64 + lane];
        float xf[8];
        #pragma unroll
        for (int j = 0; j < 8; ++j)   // B-frag: k = kgrp*8+j, n = col
            xf[j] = xcol[(size_t)(kb * 32 + kgrp * 8 + j) * HWN];
        short8 bfr;
        #pragma unroll
        for (int j = 0; j < 8; ++j) bfr[j] = f2bf(xf[j]);
        accA = __builtin_amdgcn_mfma_f32_16x16x32_bf16(afA, bfr, accA, 0, 0, 0);
        accB = __builtin_amdgcn_mfma_f32_16x16x32_bf16(afB, bfr, accB, 0, 0, 0);
    }
    __syncthreads();                  // c0s ready

    // C/D: col = lane&15, row = (lane>>4)*4 + r; accA rows=protos, accB +16
    float v[8];
    float pm = -1e30f;
    #pragma unroll
    for (int r = 0; r < 4; ++r) {
        const int row = kgrp * 4 + r;
        const float tA = accA[r] + c0s[row];
        const float tB = accB[r] + c0s[row + 16];
        v[r] = tA;
        v[r + 4] = tB;
        pm = fmaxf(pm, fmaxf(tA, tB));
        __builtin_nontemporal_store(tA,
            sim + ((size_t)b * PP + row) * HWN + nw + col);
        if (row + 16 < PP)
            __builtin_nontemporal_store(tB,
                sim + ((size_t)b * PP + row + 16) * HWN + nw + col);
    }
    // cross-lane max/sum over the 4 k-groups (pos fixed = col)
    float m = pm;
    m = fmaxf(m, __shfl_xor(m, 16));
    m = fmaxf(m, __shfl_xor(m, 32));

    float s = 0.f;
    #pragma unroll
    for (int r = 0; r < 8; ++r)       // pads: exp(-huge) = 0
        s += __expf((v[r] - m) * (1.f / 6.f));
    s += __shfl_xor(s, 16);
    s += __shfl_xor(s, 32);

    if (lane < 16)                    // max_p softmax == 1/sum exp
        wq[(size_t)b * HWN + nw + col] = 1.f / s;
}

// ---- kernel 3 (B): pure streaming out0 = X * w ------------------------------
// Flat f32x4 grid: 4096 blocks x 256 threads x 8 chunks (stride 2^20 chunks).
// Contiguous 4KB per wave-instr; w from L2 (512 KB, reused 256x); nt stores.
__global__ __launch_bounds__(256) void scale_kernel(
    const float* __restrict__ X,     // [B,C,HW]
    const float* __restrict__ wq,    // [B,HWN]
    float* __restrict__ out0)        // [B,C,HW]
{
    const int t = blockIdx.x * 256 + threadIdx.x;   // 0 .. 2^20-1
    const f32x4* X4 = (const f32x4*)X;
    const f32x4* W4 = (const f32x4*)wq;
    f32x4*       O4 = (f32x4*)out0;

    #pragma unroll
    for (int k = 0; k < 8; ++k) {
        const int i  = t + (k << 20);     // chunk index; 2^20 chunks per batch
        const int b  = i >> 20;           // CC*HWN/4 = 2^20
        const int n4 = i & 4095;          // HWN/4 = 4096
        const f32x4 x = X4[i];
        const f32x4 w = W4[(b << 12) + n4];
        __builtin_nontemporal_store(x * w, &O4[i]);
    }
}

extern "C" void kernel_launch(void* const* d_in, const int* in_sizes, int n_in,
                              void* d_out, int out_size, void* d_ws, size_t ws_size,
                              hipStream_t stream) {
    const float* X     = (const float*)d_in[0];
    const float* proto = (const float*)d_in[1];
    const float* Wk    = (const float*)d_in[2];
    const float* bk    = (const float*)d_in[3];
    const float* Wq    = (const float*)d_in[4];
    const float* bq    = (const float*)d_in[5];

    float* out  = (float*)d_out;
    float* qout = out + OFF_Q;
    float* sim  = out + OFF_SIM;

    short* Afrag = (short*)d_ws;                           // 65536 shorts
    float* c0    = (float*)(Afrag + BB * 2 * 8 * 64 * 8);  // 256 floats
    float* wq    = c0 + BB * PPAD;                         // 131072 floats

    proj_kernel<<<PPAD * BB, 256, 0, stream>>>(proto, Wq, bq, Wk, bk, qout, Afrag, c0);

    dim3 gridA(HWN / 64, BB);                              // 256 x 8 = 2048
    sim_kernel<<<gridA, 256, 0, stream>>>(X, Afrag, c0, wq, sim);

    scale_kernel<<<4096, 256, 0, stream>>>(X, wq, out);
}

// Round 13
// 71.339 us; speedup vs baseline: 1.3041x; 1.2827x over previous
//
#include <hip/hip_runtime.h>

#define BB    8
#define CC    256
#define HWN   16384       // 128*128
#define PP    30
#define PPAD  32          // padded proto count (2 zero rows)
#define KD    128
#define GG    5
// d_out float offsets
#define OFF_Q   (33554432u)             // 8*256*128*128
#define OFF_SIM (OFF_Q + 30720u)        // + 30*8*128

typedef float  f32x4 __attribute__((ext_vector_type(4)));
typedef short  short8 __attribute__((ext_vector_type(8)));

static __device__ __forceinline__ short f2bf(float f) {   // f32 -> bf16 RNE
    unsigned u = __float_as_uint(f);
    u += 0x7fffu + ((u >> 16) & 1u);
    return (short)(u >> 16);
}

// ---- kernel 1: q-projection + A in bf16 16x16x32-fragment order + c0 -------
// A[b,p,c] = sum_k q[p,b,k]*Wk[k,c]  (rows 30,31 zero)
// A-frag layout for v_mfma_f32_16x16x32_bf16 (half h = p>>4):
//   kb = c>>5, lane = (p&15) + 16*((c>>3)&3), j = c&7
//   Afrag[(((b*2 + h)*8 + kb)*64 + lane)*8 + j]
__global__ __launch_bounds__(256) void proj_kernel(
    const float* __restrict__ proto,  // [P,B,C]
    const float* __restrict__ Wq,     // [6,128,C]
    const float* __restrict__ bq,     // [6,128]
    const float* __restrict__ Wk,     // [128,C]
    const float* __restrict__ bk,     // [128]
    float* __restrict__ qout,         // [P,B,128] (into d_out)
    short* __restrict__ Afrag,        // [B,2,8,64,8] bf16 (ws)
    float* __restrict__ c0)           // [B,PPAD]   (ws)
{
    const int pb = blockIdx.x;        // p*B + b  (p in [0,32))
    const int p = pb / BB, b = pb % BB;
    const int tid = threadIdx.x;      // = channel c

    const int kb = tid >> 5, sub = (tid >> 3) & 3, j = tid & 7;
    const int lane = (p & 15) + 16 * sub;
    const size_t fidx = (((size_t)(b * 2 + (p >> 4)) * 8 + kb) * 64 + lane) * 8 + j;

    if (p >= PP) {                    // pad rows
        Afrag[fidx] = 0;
        if (tid == 0) c0[b * PPAD + p] = -1e30f;
        return;
    }
    const int g = p / GG;

    __shared__ float ps[CC];
    __shared__ float qs[KD];

    for (int c = tid; c < CC; c += 256)
        ps[c] = proto[(size_t)(p * BB + b) * CC + c];
    __syncthreads();

    if (tid < KD) {
        const float* wrow = Wq + (size_t)(g * KD + tid) * CC;
        float a = 0.f;
        #pragma unroll 4
        for (int c = 0; c < CC; ++c) a += ps[c] * wrow[c];
        a += bq[g * KD + tid];
        qout[(size_t)(p * BB + b) * KD + tid] = a;
        qs[tid] = a;
    }
    __syncthreads();

    float a = 0.f;
    #pragma unroll 4
    for (int k = 0; k < KD; ++k) a += qs[k] * Wk[k * CC + tid];
    Afrag[fidx] = f2bf(a);

    if (tid == 0) {
        float s = 0.f;
        for (int k = 0; k < KD; ++k) s += qs[k] * bk[k];
        c0[b * PPAD + p] = s;
    }
}

// ---- kernel 2: LDS-staged MFMA sim + softmax + out0 from LDS ---------------
// Block = 256 threads / 4 waves / 64 positions. Phase 1: stage X tile
// [256ch][64pos] (64KB LDS) with coalesced f32x4 loads. Phase 2: wave w does
// 16 positions via 8 K-steps x 2 mfma_f32_16x16x32_bf16, B-frags from LDS;
// softmax in-register (shfl_xor over k-groups). Phase 3: out0 = Xs * w
// straight from LDS (no second global X read), nt f32x4 streams.
__global__ __launch_bounds__(256) void fused_kernel(
    const float* __restrict__ X,     // [B,C,HW]
    const short* __restrict__ Afrag, // [B,2,8,64,8] bf16
    const float* __restrict__ c0,    // [B,PPAD]
    float* __restrict__ out0,        // [B,C,HW]
    float* __restrict__ sim)         // [B,PP,HW]
{
    const int b    = blockIdx.y;
    const int tid  = threadIdx.x;
    const int lane = tid & 63;
    const int wid  = tid >> 6;
    const int col  = lane & 15;       // position within wave tile
    const int kgrp = lane >> 4;       // 0..3 (k-subchunk)
    const int n0   = blockIdx.x * 64;

    __shared__ float Xs[CC][64];      // 64 KB
    __shared__ float c0s[PPAD];
    __shared__ float wbuf[64];

    if (tid < PPAD) c0s[tid] = c0[b * PPAD + tid];

    // ---- phase 1: stage X tile (16 f32x4 per thread, 4-deep batches) ----
    {
        const float* gb = X + (size_t)b * CC * HWN + n0;
        #pragma unroll
        for (int it = 0; it < 4; ++it) {
            f32x4 v[4];
            #pragma unroll
            for (int u = 0; u < 4; ++u) {
                const int flat = (it * 4 + u) * 256 + tid;
                const int ch = flat >> 4, pq = flat & 15;
                v[u] = *(const f32x4*)(gb + (size_t)ch * HWN + pq * 4);
            }
            #pragma unroll
            for (int u = 0; u < 4; ++u) {
                const int flat = (it * 4 + u) * 256 + tid;
                *(f32x4*)(&Xs[0][0] + (size_t)flat * 4) = v[u];
            }
        }
    }
    __syncthreads();

    // ---- phase 2: MFMA + softmax ----
    const short8* af8 = (const short8*)Afrag;
    const size_t afbase = (size_t)b * 2 * 8 * 64;

    f32x4 accA = {}, accB = {};
    #pragma unroll 2
    for (int kb = 0; kb < 8; ++kb) {
        const short8 afA = af8[afbase + (size_t)kb * 64 + lane];
        const short8 afB = af8[afbase + (size_t)(8 + kb) * 64 + lane];
        short8 bfr;
        #pragma unroll
        for (int j = 0; j < 8; ++j)   // B-frag: k = kgrp*8+j, n = col
            bfr[j] = f2bf(Xs[kb * 32 + kgrp * 8 + j][wid * 16 + col]);
        accA = __builtin_amdgcn_mfma_f32_16x16x32_bf16(afA, bfr, accA, 0, 0, 0);
        accB = __builtin_amdgcn_mfma_f32_16x16x32_bf16(afB, bfr, accB, 0, 0, 0);
    }

    // C/D: col = lane&15, row = (lane>>4)*4 + r; accA rows=protos, accB +16
    const int nw = n0 + wid * 16;
    float v[8];
    float pm = -1e30f;
    #pragma unroll
    for (int r = 0; r < 4; ++r) {
        const int row = kgrp * 4 + r;
        const float tA = accA[r] + c0s[row];
        const float tB = accB[r] + c0s[row + 16];
        v[r] = tA;
        v[r + 4] = tB;
        pm = fmaxf(pm, fmaxf(tA, tB));
        __builtin_nontemporal_store(tA,
            sim + ((size_t)b * PP + row) * HWN + nw + col);
        if (row + 16 < PP)
            __builtin_nontemporal_store(tB,
                sim + ((size_t)b * PP + row + 16) * HWN + nw + col);
    }
    float m = pm;
    m = fmaxf(m, __shfl_xor(m, 16));
    m = fmaxf(m, __shfl_xor(m, 32));

    float s = 0.f;
    #pragma unroll
    for (int r = 0; r < 8; ++r)       // pads: exp(-huge) = 0
        s += __expf((v[r] - m) * (1.f / 6.f));
    s += __shfl_xor(s, 16);
    s += __shfl_xor(s, 32);

    if (lane < 16) wbuf[wid * 16 + lane] = 1.f / s;  // max softmax == 1/sum
    __syncthreads();

    // ---- phase 3: out0 = Xs * w from LDS ----
    const int pq = tid & 15, cg = tid >> 4;
    const f32x4 w4 = *(const f32x4*)(&wbuf[pq * 4]);
    float* ob = out0 + (size_t)b * CC * HWN + n0 + pq * 4;
    #pragma unroll 4
    for (int i = 0; i < 16; ++i) {
        const int ch = cg * 16 + i;
        f32x4 x = *(const f32x4*)(&Xs[ch][pq * 4]);
        __builtin_nontemporal_store(x * w4, (f32x4*)(ob + (size_t)ch * HWN));
    }
}

extern "C" void kernel_launch(void* const* d_in, const int* in_sizes, int n_in,
                              void* d_out, int out_size, void* d_ws, size_t ws_size,
                              hipStream_t stream) {
    const float* X     = (const float*)d_in[0];
    const float* proto = (const float*)d_in[1];
    const float* Wk    = (const float*)d_in[2];
    const float* bk    = (const float*)d_in[3];
    const float* Wq    = (const float*)d_in[4];
    const float* bq    = (const float*)d_in[5];

    float* out  = (float*)d_out;
    float* qout = out + OFF_Q;
    float* sim  = out + OFF_SIM;

    short* Afrag = (short*)d_ws;                           // 65536 shorts
    float* c0    = (float*)(Afrag + BB * 2 * 8 * 64 * 8);  // 256 floats

    proj_kernel<<<PPAD * BB, 256, 0, stream>>>(proto, Wq, bq, Wk, bk, qout, Afrag, c0);

    dim3 grid(HWN / 64, BB);                               // 256 x 8 = 2048
    fused_kernel<<<grid, 256, 0, stream>>>(X, Afrag, c0, out, sim);
}

// Round 14
// 69.005 us; speedup vs baseline: 1.3482x; 1.0338x over previous
//
#include <hip/hip_runtime.h>

#define BB    8
#define CC    256
#define HWN   16384       // 128*128
#define PP    30
#define PPAD  32          // padded proto count (2 zero rows)
#define KD    128
#define GG    5
#define XsS   66          // LDS row stride in shorts (33 dwords, odd -> conflict-free)
// d_out float offsets
#define OFF_Q   (33554432u)             // 8*256*128*128
#define OFF_SIM (OFF_Q + 30720u)        // + 30*8*128

typedef float  f32x4 __attribute__((ext_vector_type(4)));
typedef short  short8 __attribute__((ext_vector_type(8)));

static __device__ __forceinline__ unsigned short f2bf(float f) { // f32->bf16 RNE
    unsigned u = __float_as_uint(f);
    u += 0x7fffu + ((u >> 16) & 1u);
    return (unsigned short)(u >> 16);
}

// ---- kernel 1: q-projection + A in bf16 16x16x32-fragment order + c0 -------
// A[b,p,c] = sum_k q[p,b,k]*Wk[k,c]  (rows 30,31 zero)
// A-frag layout for v_mfma_f32_16x16x32_bf16 (half h = p>>4):
//   kb = c>>5, lane = (p&15) + 16*((c>>3)&3), j = c&7
//   Afrag[(((b*2 + h)*8 + kb)*64 + lane)*8 + j]
__global__ __launch_bounds__(256) void proj_kernel(
    const float* __restrict__ proto,  // [P,B,C]
    const float* __restrict__ Wq,     // [6,128,C]
    const float* __restrict__ bq,     // [6,128]
    const float* __restrict__ Wk,     // [128,C]
    const float* __restrict__ bk,     // [128]
    float* __restrict__ qout,         // [P,B,128] (into d_out)
    short* __restrict__ Afrag,        // [B,2,8,64,8] bf16 (ws)
    float* __restrict__ c0)           // [B,PPAD]   (ws)
{
    const int pb = blockIdx.x;        // p*B + b  (p in [0,32))
    const int p = pb / BB, b = pb % BB;
    const int tid = threadIdx.x;      // = channel c

    const int kb = tid >> 5, sub = (tid >> 3) & 3, j = tid & 7;
    const int lane = (p & 15) + 16 * sub;
    const size_t fidx = (((size_t)(b * 2 + (p >> 4)) * 8 + kb) * 64 + lane) * 8 + j;

    if (p >= PP) {                    // pad rows
        Afrag[fidx] = 0;
        if (tid == 0) c0[b * PPAD + p] = -1e30f;
        return;
    }
    const int g = p / GG;

    __shared__ float ps[CC];
    __shared__ float qs[KD];

    for (int c = tid; c < CC; c += 256)
        ps[c] = proto[(size_t)(p * BB + b) * CC + c];
    __syncthreads();

    if (tid < KD) {
        const float* wrow = Wq + (size_t)(g * KD + tid) * CC;
        float a = 0.f;
        #pragma unroll 4
        for (int c = 0; c < CC; ++c) a += ps[c] * wrow[c];
        a += bq[g * KD + tid];
        qout[(size_t)(p * BB + b) * KD + tid] = a;
        qs[tid] = a;
    }
    __syncthreads();

    float a = 0.f;
    #pragma unroll 4
    for (int k = 0; k < KD; ++k) a += qs[k] * Wk[k * CC + tid];
    Afrag[fidx] = (short)f2bf(a);

    if (tid == 0) {
        float s = 0.f;
        for (int k = 0; k < KD; ++k) s += qs[k] * bk[k];
        c0[b * PPAD + p] = s;
    }
}

// ---- kernel 2: bf16-LDS-staged MFMA sim + softmax + out0 from LDS ----------
// Block = 256 threads / 4 waves / 64 positions; 33 KB LDS -> 4 blocks/CU.
// Phase 1: stage X tile as bf16 [256ch][stride 66] (coalesced f32x4 loads,
// packed u32 LDS writes). Phase 2: wave w: 16 pos via 8 K-steps x 2
// mfma_f32_16x16x32_bf16, B-frags as u16 LDS reads; softmax via shfl_xor.
// Phase 3: out0 = unpack(Xs) * w, nt f32x4 streams (no 2nd global X read).
__global__ __launch_bounds__(256) void fused_kernel(
    const float* __restrict__ X,     // [B,C,HW]
    const short* __restrict__ Afrag, // [B,2,8,64,8] bf16
    const float* __restrict__ c0,    // [B,PPAD]
    float* __restrict__ out0,        // [B,C,HW]
    float* __restrict__ sim)         // [B,PP,HW]
{
    const int b    = blockIdx.y;
    const int tid  = threadIdx.x;
    const int lane = tid & 63;
    const int wid  = tid >> 6;
    const int col  = lane & 15;       // position within wave tile
    const int kgrp = lane >> 4;       // 0..3 (k-subchunk)
    const int n0   = blockIdx.x * 64;

    __shared__ unsigned short Xs[CC * XsS];   // 33792 B
    __shared__ float c0s[PPAD];
    __shared__ float wbuf[64];

    if (tid < PPAD) c0s[tid] = c0[b * PPAD + tid];

    // ---- phase 1: stage X tile as bf16 (16 f32x4 per thread, batched 4) ----
    {
        const float* gb = X + (size_t)b * CC * HWN + n0;
        #pragma unroll
        for (int it = 0; it < 4; ++it) {
            f32x4 v[4];
            #pragma unroll
            for (int u = 0; u < 4; ++u) {
                const int flat = (it * 4 + u) * 256 + tid;   // 0..4095
                const int ch = flat >> 4, pq = flat & 15;
                v[u] = *(const f32x4*)(gb + (size_t)ch * HWN + pq * 4);
            }
            #pragma unroll
            for (int u = 0; u < 4; ++u) {
                const int flat = (it * 4 + u) * 256 + tid;
                const int ch = flat >> 4, pq = flat & 15;
                const unsigned lo = (unsigned)f2bf(v[u].x) | ((unsigned)f2bf(v[u].y) << 16);
                const unsigned hi = (unsigned)f2bf(v[u].z) | ((unsigned)f2bf(v[u].w) << 16);
                unsigned* dst = (unsigned*)&Xs[ch * XsS + pq * 4];
                dst[0] = lo;
                dst[1] = hi;
            }
        }
    }
    __syncthreads();

    // ---- phase 2: MFMA + softmax ----
    const short8* af8 = (const short8*)Afrag;
    const size_t afbase = (size_t)b * 2 * 8 * 64;

    f32x4 accA = {}, accB = {};
    #pragma unroll 2
    for (int kb = 0; kb < 8; ++kb) {
        const short8 afA = af8[afbase + (size_t)kb * 64 + lane];
        const short8 afB = af8[afbase + (size_t)(8 + kb) * 64 + lane];
        short8 bfr;
        #pragma unroll
        for (int j = 0; j < 8; ++j)   // B-frag: k = kgrp*8+j, n = col
            bfr[j] = (short)Xs[(kb * 32 + kgrp * 8 + j) * XsS + wid * 16 + col];
        accA = __builtin_amdgcn_mfma_f32_16x16x32_bf16(afA, bfr, accA, 0, 0, 0);
        accB = __builtin_amdgcn_mfma_f32_16x16x32_bf16(afB, bfr, accB, 0, 0, 0);
    }

    // C/D: col = lane&15, row = (lane>>4)*4 + r; accA rows=protos, accB +16
    const int nw = n0 + wid * 16;
    float v[8];
    float pm = -1e30f;
    #pragma unroll
    for (int r = 0; r < 4; ++r) {
        const int row = kgrp * 4 + r;
        const float tA = accA[r] + c0s[row];
        const float tB = accB[r] + c0s[row + 16];
        v[r] = tA;
        v[r + 4] = tB;
        pm = fmaxf(pm, fmaxf(tA, tB));
        __builtin_nontemporal_store(tA,
            sim + ((size_t)b * PP + row) * HWN + nw + col);
        if (row + 16 < PP)
            __builtin_nontemporal_store(tB,
                sim + ((size_t)b * PP + row + 16) * HWN + nw + col);
    }
    float m = pm;
    m = fmaxf(m, __shfl_xor(m, 16));
    m = fmaxf(m, __shfl_xor(m, 32));

    float s = 0.f;
    #pragma unroll
    for (int r = 0; r < 8; ++r)       // pads: exp(-huge) = 0
        s += __expf((v[r] - m) * (1.f / 6.f));
    s += __shfl_xor(s, 16);
    s += __shfl_xor(s, 32);

    if (lane < 16) wbuf[wid * 16 + lane] = 1.f / s;  // max softmax == 1/sum
    __syncthreads();

    // ---- phase 3: out0 = unpack(Xs) * w from LDS ----
    const int pq = tid & 15, cg = tid >> 4;
    const f32x4 w4 = *(const f32x4*)(&wbuf[pq * 4]);
    float* ob = out0 + (size_t)b * CC * HWN + n0 + pq * 4;
    #pragma unroll 4
    for (int i = 0; i < 16; ++i) {
        const int ch = cg * 16 + i;
        const unsigned* src = (const unsigned*)&Xs[ch * XsS + pq * 4];
        const unsigned lo = src[0], hi = src[1];
        f32x4 x;
        x.x = __uint_as_float(lo << 16);
        x.y = __uint_as_float(lo & 0xffff0000u);
        x.z = __uint_as_float(hi << 16);
        x.w = __uint_as_float(hi & 0xffff0000u);
        __builtin_nontemporal_store(x * w4, (f32x4*)(ob + (size_t)ch * HWN));
    }
}

extern "C" void kernel_launch(void* const* d_in, const int* in_sizes, int n_in,
                              void* d_out, int out_size, void* d_ws, size_t ws_size,
                              hipStream_t stream) {
    const float* X     = (const float*)d_in[0];
    const float* proto = (const float*)d_in[1];
    const float* Wk    = (const float*)d_in[2];
    const float* bk    = (const float*)d_in[3];
    const float* Wq    = (const float*)d_in[4];
    const float* bq    = (const float*)d_in[5];

    float* out  = (float*)d_out;
    float* qout = out + OFF_Q;
    float* sim  = out + OFF_SIM;

    short* Afrag = (short*)d_ws;                           // 65536 shorts
    float* c0    = (float*)(Afrag + BB * 2 * 8 * 64 * 8);  // 256 floats

    proj_kernel<<<PPAD * BB, 256, 0, stream>>>(proto, Wq, bq, Wk, bk, qout, Afrag, c0);

    dim3 grid(HWN / 64, BB);                               // 256 x 8 = 2048
    fused_kernel<<<grid, 256, 0, stream>>>(X, Afrag, c0, out, sim);
}